// Round 5
// baseline (754.185 us; speedup 1.0000x reference)
//
#include <hip/hip_runtime.h>
#include <hip/hip_cooperative_groups.h>

namespace cg = cooperative_groups;

// GCN layer, fully-fused cooperative single-kernel pipeline (R16).
// Phases (grid.sync between): P1 chunk-hist -> P2 bucket scan -> P3 scatter ->
// P4 dis+MFMA transform -> P5 bucket gather-aggregate. Per-phase code is
// bit-identical to the R15 5-kernel version (157.2us); this removes 4 dispatch
// boundaries (drain + launch + L2 writeback) and stages W once per block.
// Fallback: if hipLaunchCooperativeKernel fails, run the R15 kernels.
// History: global atomics dead ends 3 ways (R1/R6 float, R4 LDS float, R12 int
// deg[] cross-XCD ping-pong 236us). CHUNK must stay long (R13: 6144 regressed).
// ZLD must stay 32 (R14: 96B rows straddle lines). scanB2 removed via fixed
// CAP=2048 bucket regions (R15).

#define NF 48
#define NPAIR 24           // NF/2 valid uints per node row in zp
#define ZLD 32             // zp row stride in uints (128 B aligned)
#define RB 64              // rows per bucket
#define CHUNK 16384        // edges per binning chunk (98 chunks; long scatter runs)
#define CAP 2048           // fixed per-bucket capacity in binned[] (mean 1024)
#define SCOL_CAP 2048      // per-bucket LDS col capacity

typedef __attribute__((ext_vector_type(8))) short frag_ab;   // 8 bf16
typedef __attribute__((ext_vector_type(4))) float f32x4;

__device__ inline unsigned short f2bf(float f) {
    unsigned u = __float_as_uint(f);
    u = (u + 0x7fffu + ((u >> 16) & 1u)) >> 16;   // RN-even
    return (unsigned short)u;
}

// ======================= fused cooperative kernel =======================
__global__ __launch_bounds__(512, 4)
void fused_kernel(const int* __restrict__ row, const int* __restrict__ col,
                  const float* __restrict__ x, const float* __restrict__ W,
                  const float* __restrict__ bias, float* __restrict__ out,
                  unsigned* zpw, unsigned* __restrict__ binned,
                  float* __restrict__ dis, int* __restrict__ blkhist,
                  int* __restrict__ btotal, int* __restrict__ lrp_g,
                  int N, int E, int NBUK, int NCH) {
    extern __shared__ char smem[];     // dyn: max(NBUK*4, 14336) bytes
    __shared__ int   sHist[RB];
    __shared__ float sDis[RB];
    __shared__ int   sLrp[RB + 1];
    __shared__ int   sCur[RB];

    cg::grid_group grid = cg::this_grid();
    const int tid = threadIdx.x;
    const int bid = blockIdx.x;
    const int G = gridDim.x;

    // chunk ownership: chunk c handled by the unique block with c in [c_lo,c_hi)
    // (spreads the NCH chunks evenly across the whole block-id range, robust to
    //  any block->CU placement)
    const int c_lo = (int)(((long long)bid * NCH) / G);
    const int c_hi = (int)(((long long)(bid + 1) * NCH) / G);

    // ---------------- P1: per-chunk bucket histogram ----------------
    {
        int* hist = (int*)smem;        // NBUK ints
        for (int c = c_lo; c < c_hi; ++c) {
            for (int i = tid; i < NBUK; i += 512) hist[i] = 0;
            __syncthreads();
            int s = c * CHUNK, t = min(E, s + CHUNK);
            int nv = (t - s) >> 2;
            const int4* r4 = (const int4*)(row + s);
            for (int i = tid; i < nv; i += 512) {
                int4 r = r4[i];
                atomicAdd(&hist[r.x >> 6], 1);
                atomicAdd(&hist[r.y >> 6], 1);
                atomicAdd(&hist[r.z >> 6], 1);
                atomicAdd(&hist[r.w >> 6], 1);
            }
            for (int e = s + nv * 4 + tid; e < t; e += 512)
                atomicAdd(&hist[row[e] >> 6], 1);
            __syncthreads();
            int* dst = blkhist + (size_t)c * NBUK;
            for (int k = tid; k < NBUK; k += 512) dst[k] = hist[k];
            __syncthreads();
        }
    }
    __threadfence();
    grid.sync();

    // ---------------- P2: per-bucket exclusive scan over chunks ----------------
    {
        int w = bid * 8 + (tid >> 6);  // global wave id == bucket
        int lane = tid & 63;
        if (w < NBUK) {
            int carry = 0;
            for (int base = 0; base < NCH; base += 64) {
                int i = base + lane;
                int v = (i < NCH) ? blkhist[(size_t)i * NBUK + w] : 0;
                int incl = v;
                #pragma unroll
                for (int off = 1; off < 64; off <<= 1) {
                    int u = __shfl_up(incl, off, 64);
                    if (lane >= off) incl += u;
                }
                if (i < NCH) blkhist[(size_t)i * NBUK + w] = carry + incl - v;
                carry += __shfl(incl, 63, 64);
            }
            if (lane == 0) btotal[w] = carry;
        }
    }
    __threadfence();
    grid.sync();

    // ---------------- P3: scatter to fixed-CAP bucket regions ----------------
    {
        int* cur = (int*)smem;         // NBUK ints
        for (int c = c_lo; c < c_hi; ++c) {
            const int* boff = blkhist + (size_t)c * NBUK;
            for (int k = tid; k < NBUK; k += 512) cur[k] = k * CAP + boff[k];
            __syncthreads();
            int s = c * CHUNK, t = min(E, s + CHUNK);
            int nv = (t - s) >> 2;
            const int4* r4 = (const int4*)(row + s);
            const int4* c4 = (const int4*)(col + s);
            for (int i = tid; i < nv; i += 512) {
                int4 r = r4[i];
                int4 cc = c4[i];
                unsigned k0 = (unsigned)r.x >> 6;
                int p0 = atomicAdd(&cur[k0], 1);
                if (p0 < (int)((k0 + 1) * CAP))
                    binned[p0] = ((unsigned)(r.x & (RB - 1)) << 26) | (unsigned)cc.x;
                unsigned k1 = (unsigned)r.y >> 6;
                int p1 = atomicAdd(&cur[k1], 1);
                if (p1 < (int)((k1 + 1) * CAP))
                    binned[p1] = ((unsigned)(r.y & (RB - 1)) << 26) | (unsigned)cc.y;
                unsigned k2 = (unsigned)r.z >> 6;
                int p2 = atomicAdd(&cur[k2], 1);
                if (p2 < (int)((k2 + 1) * CAP))
                    binned[p2] = ((unsigned)(r.z & (RB - 1)) << 26) | (unsigned)cc.z;
                unsigned k3 = (unsigned)r.w >> 6;
                int p3 = atomicAdd(&cur[k3], 1);
                if (p3 < (int)((k3 + 1) * CAP))
                    binned[p3] = ((unsigned)(r.w & (RB - 1)) << 26) | (unsigned)cc.w;
            }
            for (int e = s + nv * 4 + tid; e < t; e += 512) {
                int r = row[e], c2 = col[e];
                unsigned k0 = (unsigned)r >> 6;
                int pos = atomicAdd(&cur[k0], 1);
                if (pos < (int)((k0 + 1) * CAP))
                    binned[pos] = ((unsigned)(r & (RB - 1)) << 26) | (unsigned)c2;
            }
            __syncthreads();
        }
    }
    __threadfence();
    grid.sync();

    // ---------------- P4: dis + MFMA transform (W staged once) ----------------
    {
        unsigned short* Xb = (unsigned short*)smem;            // 8 KB
        unsigned short* Wb = (unsigned short*)(smem + 8192);   // 6 KB
        unsigned short* zp16 = (unsigned short*)zpw;
        const float4* W4 = (const float4*)W;
        for (int i = tid; i < 576; i += 512) {
            int r = i / 12, c = i % 12;
            float4 v = W4[r * 12 + c];
            unsigned short* d = &Wb[r * 64 + c * 4];
            d[0] = f2bf(v.x); d[1] = f2bf(v.y); d[2] = f2bf(v.z); d[3] = f2bf(v.w);
        }
        for (int i = tid; i < 48 * 8; i += 512)
            ((unsigned*)Wb)[(i >> 3) * 32 + 24 + (i & 7)] = 0u;
        const float4* x4 = (const float4*)x;
        for (int b4 = bid; b4 < NBUK; b4 += G) {
            const int nb0 = b4 * RB;
            const int s = b4 * CAP;
            const int t = s + min(btotal[b4], CAP);
            if (tid < RB) sHist[tid] = 0;
            __syncthreads();               // also covers Wb staging on first iter
            for (int e = s + tid; e < t; e += 512)
                atomicAdd(&sHist[binned[e] >> 26], 1);
            for (int i = tid; i < 768; i += 512) {
                int r = i / 12, c = i % 12;
                int n = nb0 + r;
                float4 v = (n < N) ? x4[(size_t)n * 12 + c] : make_float4(0.f, 0.f, 0.f, 0.f);
                unsigned short* d = &Xb[r * 64 + c * 4];
                d[0] = f2bf(v.x); d[1] = f2bf(v.y); d[2] = f2bf(v.z); d[3] = f2bf(v.w);
            }
            for (int i = tid; i < 64 * 8; i += 512)
                ((unsigned*)Xb)[(i >> 3) * 32 + 24 + (i & 7)] = 0u;
            __syncthreads();
            if (tid < RB) {
                int v = sHist[tid];
                int incl = v;
                #pragma unroll
                for (int off = 1; off < 64; off <<= 1) {
                    int u = __shfl_up(incl, off, 64);
                    if (tid >= off) incl += u;
                }
                int* lp = lrp_g + (size_t)b4 * (RB + 1);
                lp[tid] = incl - v;
                if (tid == RB - 1) lp[RB] = incl;
                float dv = (v > 0) ? rsqrtf((float)v) : 0.0f;
                sDis[tid] = dv;
                int n = nb0 + tid;
                if (n < N) dis[n] = dv;
            }
            __syncthreads();
            if (tid < 256) {               // waves 0-3: MFMA + store
                const int wv = tid >> 6, lane = tid & 63;
                const int quad = lane >> 4, l16 = lane & 15;
                const int mrow = wv * 16 + l16;
                frag_ab A0 = *(const frag_ab*)&Xb[mrow * 64 + quad * 8];
                frag_ab A1 = *(const frag_ab*)&Xb[mrow * 64 + 32 + quad * 8];
                f32x4 acc[3];
                #pragma unroll
                for (int tt = 0; tt < 3; tt++) {
                    frag_ab B0 = *(const frag_ab*)&Wb[(tt * 16 + l16) * 64 + quad * 8];
                    frag_ab B1 = *(const frag_ab*)&Wb[(tt * 16 + l16) * 64 + 32 + quad * 8];
                    f32x4 z = {0.f, 0.f, 0.f, 0.f};
                    z = __builtin_amdgcn_mfma_f32_16x16x32_bf16(A0, B0, z, 0, 0, 0);
                    z = __builtin_amdgcn_mfma_f32_16x16x32_bf16(A1, B1, z, 0, 0, 0);
                    acc[tt] = z;
                }
                #pragma unroll
                for (int r = 0; r < 4; r++) {   // D: col=lane&15, row=quad*4+r
                    int lrow = wv * 16 + quad * 4 + r;
                    int n = nb0 + lrow;
                    if (n < N) {
                        float dn = sDis[lrow];
                        unsigned short* zr = zp16 + (size_t)n * (2 * ZLD);
                        #pragma unroll
                        for (int tt = 0; tt < 3; tt++)
                            zr[tt * 16 + l16] = f2bf(dn * acc[tt][r]);
                        zr[48 + l16] = 0;       // feature pad -> full-line writes
                    }
                }
            }
            __syncthreads();
        }
    }
    __threadfence();
    grid.sync();

    // ---------------- P5: gather aggregate ----------------
    {
        int* scol = (int*)smem;        // 8 KB
        const unsigned* zp = (const unsigned*)zpw;
        const int lane = tid & 63;
        const int wave = tid >> 6;     // 0..7
        const int h = lane >> 5;       // half-wave: edge parity
        const int j = lane & 31;       // feature-pair index (24..31 = pad lanes)
        const bool act = (j < NPAIR);
        const int ja = act ? j : 0;
        float bb0 = 0.0f, bb1 = 0.0f;
        if (act) { bb0 = bias[2 * j]; bb1 = bias[2 * j + 1]; }
        for (int b5 = bid; b5 < NBUK; b5 += G) {
            const int s = b5 * CAP;
            const int cnt = btotal[b5];
            const int t = s + min(cnt, CAP);
            if (tid < RB + 1) {
                int v = lrp_g[(size_t)b5 * (RB + 1) + tid];
                sLrp[tid] = v;
                if (tid < RB) sCur[tid] = v;
            }
            __syncthreads();
            const bool sorted_ok = (cnt <= SCOL_CAP);
            if (sorted_ok) {
                for (int e = s + tid; e < t; e += 512) {
                    unsigned rc = binned[e];
                    int pos = atomicAdd(&sCur[rc >> 26], 1);
                    scol[pos] = (int)((rc & 0x3ffffffu) << 5);   // pre-mult x32
                }
            }
            __syncthreads();
            const int rbase = b5 * RB;
            for (int ri = wave; ri < RB; ri += 8) {
                int r = rbase + ri;
                if (r >= N) break;
                float a0 = 0.0f, a1 = 0.0f;
                if (sorted_ok) {
                    int ks = sLrp[ri], ke = sLrp[ri + 1];
                    int k = ks + h;
                    for (; k + 6 < ke; k += 8) {
                        int c0 = scol[k];
                        int c1 = scol[k + 2];
                        int c2 = scol[k + 4];
                        int c3 = scol[k + 6];
                        unsigned u0 = zp[(size_t)c0 + ja];
                        unsigned u1 = zp[(size_t)c1 + ja];
                        unsigned u2 = zp[(size_t)c2 + ja];
                        unsigned u3 = zp[(size_t)c3 + ja];
                        a0 += (__uint_as_float(u0 << 16) + __uint_as_float(u1 << 16)) +
                              (__uint_as_float(u2 << 16) + __uint_as_float(u3 << 16));
                        a1 += (__uint_as_float(u0 & 0xffff0000u) + __uint_as_float(u1 & 0xffff0000u)) +
                              (__uint_as_float(u2 & 0xffff0000u) + __uint_as_float(u3 & 0xffff0000u));
                    }
                    for (; k < ke; k += 2) {
                        int c0 = scol[k];
                        unsigned u0 = zp[(size_t)c0 + ja];
                        a0 += __uint_as_float(u0 << 16);
                        a1 += __uint_as_float(u0 & 0xffff0000u);
                    }
                } else {               // overflow fallback (statistically unreachable)
                    for (int e = s; e < t; e++) {
                        unsigned rc = binned[e];
                        if ((int)(rc >> 26) == ri && h == 0 && act) {
                            unsigned u0 = zp[((size_t)(rc & 0x3ffffffu) << 5) + ja];
                            a0 += __uint_as_float(u0 << 16);
                            a1 += __uint_as_float(u0 & 0xffff0000u);
                        }
                    }
                }
                a0 += __shfl_xor(a0, 32, 64);
                a1 += __shfl_xor(a1, 32, 64);
                if (h == 0 && act) {
                    float dr = dis[r];
                    float v0 = dr * a0 + bb0;
                    float v1 = dr * a1 + bb1;
                    float2 o;
                    o.x = v0 > 0.0f ? v0 : 0.0f;
                    o.y = v1 > 0.0f ? v1 : 0.0f;
                    *(float2*)(out + (size_t)r * NF + 2 * j) = o;
                }
            }
            __syncthreads();
        }
    }
}

// ======================= R15 fallback kernels (proven 157us) =======================
__global__ void histA_kernel(const int* __restrict__ row, int* __restrict__ blkhist,
                             int NBUK, int E) {
    extern __shared__ int hist[];
    for (int i = threadIdx.x; i < NBUK; i += blockDim.x) hist[i] = 0;
    __syncthreads();
    int b = blockIdx.x;
    int s = b * CHUNK, t = min(E, s + CHUNK);
    int nv = (t - s) >> 2;
    const int4* r4 = (const int4*)(row + s);
    for (int i = threadIdx.x; i < nv; i += blockDim.x) {
        int4 r = r4[i];
        atomicAdd(&hist[r.x >> 6], 1);
        atomicAdd(&hist[r.y >> 6], 1);
        atomicAdd(&hist[r.z >> 6], 1);
        atomicAdd(&hist[r.w >> 6], 1);
    }
    for (int e = s + nv * 4 + threadIdx.x; e < t; e += blockDim.x)
        atomicAdd(&hist[row[e] >> 6], 1);
    __syncthreads();
    int* dst = blkhist + (size_t)b * NBUK;
    for (int k = threadIdx.x; k < NBUK; k += blockDim.x) dst[k] = hist[k];
}

__global__ void scanB1_kernel(int* __restrict__ blkhist, int* __restrict__ btotal,
                              int NBUK, int NCH) {
    int k = blockIdx.x;
    int lane = threadIdx.x;
    int carry = 0;
    for (int base = 0; base < NCH; base += 64) {
        int i = base + lane;
        int v = (i < NCH) ? blkhist[(size_t)i * NBUK + k] : 0;
        int incl = v;
        #pragma unroll
        for (int off = 1; off < 64; off <<= 1) {
            int u = __shfl_up(incl, off, 64);
            if (lane >= off) incl += u;
        }
        if (i < NCH) blkhist[(size_t)i * NBUK + k] = carry + incl - v;
        carry += __shfl(incl, 63, 64);
    }
    if (lane == 0) btotal[k] = carry;
}

__global__ void scatC_kernel(const int* __restrict__ row, const int* __restrict__ col,
                             const int* __restrict__ blkhist,
                             unsigned* __restrict__ binned, int NBUK, int E) {
    extern __shared__ int cur[];
    int b = blockIdx.x;
    const int* boff = blkhist + (size_t)b * NBUK;
    for (int k = threadIdx.x; k < NBUK; k += blockDim.x)
        cur[k] = k * CAP + boff[k];
    __syncthreads();
    int s = b * CHUNK, t = min(E, s + CHUNK);
    int nv = (t - s) >> 2;
    const int4* r4 = (const int4*)(row + s);
    const int4* c4 = (const int4*)(col + s);
    for (int i = threadIdx.x; i < nv; i += blockDim.x) {
        int4 r = r4[i];
        int4 c = c4[i];
        unsigned k0 = (unsigned)r.x >> 6;
        int p0 = atomicAdd(&cur[k0], 1);
        if (p0 < (int)((k0 + 1) * CAP))
            binned[p0] = ((unsigned)(r.x & (RB - 1)) << 26) | (unsigned)c.x;
        unsigned k1 = (unsigned)r.y >> 6;
        int p1 = atomicAdd(&cur[k1], 1);
        if (p1 < (int)((k1 + 1) * CAP))
            binned[p1] = ((unsigned)(r.y & (RB - 1)) << 26) | (unsigned)c.y;
        unsigned k2 = (unsigned)r.z >> 6;
        int p2 = atomicAdd(&cur[k2], 1);
        if (p2 < (int)((k2 + 1) * CAP))
            binned[p2] = ((unsigned)(r.z & (RB - 1)) << 26) | (unsigned)c.z;
        unsigned k3 = (unsigned)r.w >> 6;
        int p3 = atomicAdd(&cur[k3], 1);
        if (p3 < (int)((k3 + 1) * CAP))
            binned[p3] = ((unsigned)(r.w & (RB - 1)) << 26) | (unsigned)c.w;
    }
    for (int e = s + nv * 4 + threadIdx.x; e < t; e += blockDim.x) {
        int r = row[e], c = col[e];
        unsigned k0 = (unsigned)r >> 6;
        int pos = atomicAdd(&cur[k0], 1);
        if (pos < (int)((k0 + 1) * CAP))
            binned[pos] = ((unsigned)(r & (RB - 1)) << 26) | (unsigned)c;
    }
}

__global__ __launch_bounds__(512)
void distrans_kernel(const int* __restrict__ btotal, const unsigned* __restrict__ binned,
                     const float* __restrict__ x, const float* __restrict__ W,
                     float* __restrict__ dis, int* __restrict__ lrp_g,
                     unsigned short* __restrict__ zp16, int N) {
    __shared__ int hist[RB];
    __shared__ float disS[RB];
    __shared__ unsigned short Xb[64 * 64];
    __shared__ unsigned short Wb[48 * 64];
    const int b = blockIdx.x;
    const int tid = threadIdx.x;
    const int nb0 = b * RB;
    const int s = b * CAP;
    const int t = s + min(btotal[b], CAP);

    if (tid < RB) hist[tid] = 0;
    __syncthreads();
    for (int e = s + tid; e < t; e += 512)
        atomicAdd(&hist[binned[e] >> 26], 1);

    const float4* x4 = (const float4*)x;
    for (int i = tid; i < 768; i += 512) {
        int r = i / 12, c = i % 12;
        int n = nb0 + r;
        float4 v = (n < N) ? x4[(size_t)n * 12 + c] : make_float4(0.f, 0.f, 0.f, 0.f);
        unsigned short* d = &Xb[r * 64 + c * 4];
        d[0] = f2bf(v.x); d[1] = f2bf(v.y); d[2] = f2bf(v.z); d[3] = f2bf(v.w);
    }
    for (int i = tid; i < 64 * 8; i += 512)
        ((unsigned*)Xb)[(i >> 3) * 32 + 24 + (i & 7)] = 0u;
    const float4* W4 = (const float4*)W;
    for (int i = tid; i < 576; i += 512) {
        int r = i / 12, c = i % 12;
        float4 v = W4[r * 12 + c];
        unsigned short* d = &Wb[r * 64 + c * 4];
        d[0] = f2bf(v.x); d[1] = f2bf(v.y); d[2] = f2bf(v.z); d[3] = f2bf(v.w);
    }
    for (int i = tid; i < 48 * 8; i += 512)
        ((unsigned*)Wb)[(i >> 3) * 32 + 24 + (i & 7)] = 0u;
    __syncthreads();

    if (tid < RB) {
        int v = hist[tid];
        int incl = v;
        #pragma unroll
        for (int off = 1; off < 64; off <<= 1) {
            int u = __shfl_up(incl, off, 64);
            if (tid >= off) incl += u;
        }
        int* lp = lrp_g + (size_t)b * (RB + 1);
        lp[tid] = incl - v;
        if (tid == RB - 1) lp[RB] = incl;
        float dv = (v > 0) ? rsqrtf((float)v) : 0.0f;
        disS[tid] = dv;
        int n = nb0 + tid;
        if (n < N) dis[n] = dv;
    }
    __syncthreads();

    if (tid < 256) {
        const int wv = tid >> 6, lane = tid & 63;
        const int quad = lane >> 4, l16 = lane & 15;
        const int mrow = wv * 16 + l16;
        frag_ab A0 = *(const frag_ab*)&Xb[mrow * 64 + quad * 8];
        frag_ab A1 = *(const frag_ab*)&Xb[mrow * 64 + 32 + quad * 8];
        f32x4 acc[3];
#pragma unroll
        for (int tt = 0; tt < 3; tt++) {
            frag_ab B0 = *(const frag_ab*)&Wb[(tt * 16 + l16) * 64 + quad * 8];
            frag_ab B1 = *(const frag_ab*)&Wb[(tt * 16 + l16) * 64 + 32 + quad * 8];
            f32x4 z = {0.f, 0.f, 0.f, 0.f};
            z = __builtin_amdgcn_mfma_f32_16x16x32_bf16(A0, B0, z, 0, 0, 0);
            z = __builtin_amdgcn_mfma_f32_16x16x32_bf16(A1, B1, z, 0, 0, 0);
            acc[tt] = z;
        }
#pragma unroll
        for (int r = 0; r < 4; r++) {
            int lrow = wv * 16 + quad * 4 + r;
            int n = nb0 + lrow;
            if (n < N) {
                float dn = disS[lrow];
                unsigned short* zr = zp16 + (size_t)n * (2 * ZLD);
#pragma unroll
                for (int tt = 0; tt < 3; tt++)
                    zr[tt * 16 + l16] = f2bf(dn * acc[tt][r]);
                zr[48 + l16] = 0;
            }
        }
    }
}

__global__ __launch_bounds__(512, 8)
void aggregate_kernel(const int* __restrict__ btotal, const unsigned* __restrict__ binned,
                      const int* __restrict__ lrp_g,
                      const unsigned* __restrict__ zp, const float* __restrict__ dis,
                      const float* __restrict__ bias, float* __restrict__ out, int N) {
    __shared__ int scol[SCOL_CAP];
    __shared__ int lrp[RB + 1];
    __shared__ int cur[RB];
    const int b = blockIdx.x;
    const int s = b * CAP;
    const int cnt = btotal[b];
    const int t = s + min(cnt, CAP);
    const int tid = threadIdx.x;
    if (tid < RB + 1) {
        int v = lrp_g[(size_t)b * (RB + 1) + tid];
        lrp[tid] = v;
        if (tid < RB) cur[tid] = v;
    }
    __syncthreads();
    const bool sorted = (cnt <= SCOL_CAP);
    if (sorted) {
        for (int e = s + tid; e < t; e += 512) {
            unsigned rc = binned[e];
            int pos = atomicAdd(&cur[rc >> 26], 1);
            scol[pos] = (int)((rc & 0x3ffffffu) << 5);
        }
    }
    __syncthreads();

    const int lane = tid & 63;
    const int wave = tid >> 6;
    const int h = lane >> 5;
    const int j = lane & 31;
    const bool act = (j < NPAIR);
    const int ja = act ? j : 0;
    float bb0 = 0.0f, bb1 = 0.0f;
    if (act) { bb0 = bias[2 * j]; bb1 = bias[2 * j + 1]; }
    const int rbase = b * RB;
    for (int ri = wave; ri < RB; ri += 8) {
        int r = rbase + ri;
        if (r >= N) break;
        float a0 = 0.0f, a1 = 0.0f;
        if (sorted) {
            int ks = lrp[ri], ke = lrp[ri + 1];
            int k = ks + h;
            for (; k + 6 < ke; k += 8) {
                int c0 = scol[k];
                int c1 = scol[k + 2];
                int c2 = scol[k + 4];
                int c3 = scol[k + 6];
                unsigned u0 = zp[(size_t)c0 + ja];
                unsigned u1 = zp[(size_t)c1 + ja];
                unsigned u2 = zp[(size_t)c2 + ja];
                unsigned u3 = zp[(size_t)c3 + ja];
                a0 += (__uint_as_float(u0 << 16) + __uint_as_float(u1 << 16)) +
                      (__uint_as_float(u2 << 16) + __uint_as_float(u3 << 16));
                a1 += (__uint_as_float(u0 & 0xffff0000u) + __uint_as_float(u1 & 0xffff0000u)) +
                      (__uint_as_float(u2 & 0xffff0000u) + __uint_as_float(u3 & 0xffff0000u));
            }
            for (; k < ke; k += 2) {
                int c0 = scol[k];
                unsigned u0 = zp[(size_t)c0 + ja];
                a0 += __uint_as_float(u0 << 16);
                a1 += __uint_as_float(u0 & 0xffff0000u);
            }
        } else {
            for (int e = s; e < t; e++) {
                unsigned rc = binned[e];
                if ((int)(rc >> 26) == ri && h == 0 && act) {
                    unsigned u0 = zp[((size_t)(rc & 0x3ffffffu) << 5) + ja];
                    a0 += __uint_as_float(u0 << 16);
                    a1 += __uint_as_float(u0 & 0xffff0000u);
                }
            }
        }
        a0 += __shfl_xor(a0, 32, 64);
        a1 += __shfl_xor(a1, 32, 64);
        if (h == 0 && act) {
            float dr = dis[r];
            float v0 = dr * a0 + bb0;
            float v1 = dr * a1 + bb1;
            float2 o;
            o.x = v0 > 0.0f ? v0 : 0.0f;
            o.y = v1 > 0.0f ? v1 : 0.0f;
            *(float2*)(out + (size_t)r * NF + 2 * j) = o;
        }
    }
}

extern "C" void kernel_launch(void* const* d_in, const int* in_sizes, int n_in,
                              void* d_out, int out_size, void* d_ws, size_t ws_size,
                              hipStream_t stream) {
    const float* x    = (const float*)d_in[0];
    const int*   ei   = (const int*)d_in[1];
    const float* W    = (const float*)d_in[2];
    const float* bias = (const float*)d_in[3];
    float* out = (float*)d_out;

    const int N = in_sizes[0] / NF;
    const int E = in_sizes[1] / 2;
    const int* row = ei;
    const int* col = ei + E;
    const int NBUK = (N + RB - 1) / RB;       // 1563
    const int NCH  = (E + CHUNK - 1) / CHUNK; // 98

    // workspace layout
    char* ws = (char*)d_ws;
    unsigned* zpw     = (unsigned*)ws;       ws += (size_t)N * ZLD * 4;          // 12.8 MB
    unsigned* binned  = (unsigned*)ws;       ws += (size_t)NBUK * CAP * 4;       // 12.8 MB
    float*    dis     = (float*)ws;          ws += (size_t)N * 4;
    int*      blkhist = (int*)ws;            ws += (size_t)NCH * NBUK * 4;       // 612 KB
    int*      btotal  = (int*)ws;            ws += (size_t)NBUK * 4;
    int*      lrp_g   = (int*)ws;            ws += (size_t)NBUK * (RB + 1) * 4;  // 406 KB

    const size_t dynLds = ((size_t)NBUK * 4 > 14336) ? (size_t)NBUK * 4 : 14336;

    static int g_G = 0;                  // cooperative grid size (cached)
    if (g_G == 0) {
        int dev = 0;
        hipGetDevice(&dev);
        int nCU = 256;
        hipDeviceGetAttribute(&nCU, hipDeviceAttributeMultiprocessorCount, dev);
        int maxb = 0;
        hipError_t e = hipOccupancyMaxActiveBlocksPerMultiprocessor(
            &maxb, fused_kernel, 512, dynLds);
        if (e != hipSuccess || maxb < 1) maxb = 1;
        if (maxb > 4) maxb = 4;
        g_G = maxb * nCU;
    }

    int Np = N, Ep = E, NBUKp = NBUK, NCHp = NCH;
    void* args[] = { (void*)&row, (void*)&col, (void*)&x, (void*)&W, (void*)&bias,
                     (void*)&out, (void*)&zpw, (void*)&binned, (void*)&dis,
                     (void*)&blkhist, (void*)&btotal, (void*)&lrp_g,
                     (void*)&Np, (void*)&Ep, (void*)&NBUKp, (void*)&NCHp };
    hipError_t err = hipLaunchCooperativeKernel((const void*)fused_kernel,
                                                dim3(g_G), dim3(512), args,
                                                (unsigned)dynLds, stream);
    if (err != hipSuccess) {             // fallback: proven R15 5-kernel path
        histA_kernel<<<NCH, 512, NBUK * 4, stream>>>(row, blkhist, NBUK, E);
        scanB1_kernel<<<NBUK, 64, 0, stream>>>(blkhist, btotal, NBUK, NCH);
        scatC_kernel<<<NCH, 512, NBUK * 4, stream>>>(row, col, blkhist, binned, NBUK, E);
        distrans_kernel<<<NBUK, 512, 0, stream>>>(btotal, binned, x, W, dis, lrp_g,
                                                  (unsigned short*)zpw, N);
        aggregate_kernel<<<NBUK, 512, 0, stream>>>(btotal, binned, lrp_g, zpw, dis,
                                                   bias, out, N);
    }
}

// Round 6
// 151.936 us; speedup vs baseline: 4.9638x; 4.9638x over previous
//
#include <hip/hip_runtime.h>

// GCN layer, bucket-binned pull aggregation (register accumulate, no float atomics,
// no global int atomics):
//   binning (bucket = row>>7): chunked counting sort -> binned[] packed as
//     (row&127)<<25 | col; FIXED per-bucket capacity CAP=4096 (mean 2046, 45 sigma)
//     so bucket base = b*CAP -- no cross-bucket scan kernel.
//   distrans: one block per bucket (=128-node tile): LDS row-hist -> dis + lrp, then
//     MFMA bf16 GEMM transform (16x16x32, K 48 padded to 64, 8 waves x 16 rows);
//     writes zp rows of 64 bf16 (128 B aligned lines, features 48..63 zeroed)
//   aggregate: one block (512 thr) per bucket; LDS counting-sort by row (lrp
//     precomputed, col addrs pre-multiplied x32); full-64-lane pull-gather unroll-4,
//     fused dis*acc+bias+ReLU.
// History: global atomics dead 3 ways (R1/R6 float, R4 LDS float, R12 int deg[]
//   cross-XCD line ping-pong, 236us). CHUNK must stay long (R13: 6144 regressed).
//   ZLD must stay 32 (R14: 96B rows straddle lines). scanB2 removed via fixed-CAP
//   regions (R15, 157.2us). R16 cooperative single-kernel REGRESSED 754us:
//   grid.sync ~150us each on 8-XCD MI355X (97% occupancy, 2% busy = pure spin);
//   dispatch boundaries are ~2us -- never fuse via grid.sync here.
// R17: revert to R15 structure; RB 64->128 (scatC run length 42->84B cuts the
//   ~29MB partial-line RMW seen in R16's WRITE_SIZE; per-block fixed costs halve;
//   distrans uses all 8 waves).

#define NF 48
#define NPAIR 24           // NF/2 valid uints per node row in zp
#define ZLD 32             // zp row stride in uints (128 B aligned)
#define RB 128             // rows per bucket
#define RSH 25             // row field shift in packed entry
#define CMASK 0x1ffffffu   // col mask (25 bits; col < 2^17)
#define CHUNK 16384        // edges per binning chunk (98 chunks; long scatter runs)
#define CAP 4096           // fixed per-bucket capacity in binned[] (mean 2046)
#define SCOL_CAP 4096      // per-bucket LDS col capacity (16 KB)

typedef __attribute__((ext_vector_type(8))) short frag_ab;   // 8 bf16
typedef __attribute__((ext_vector_type(4))) float f32x4;

__device__ inline unsigned short f2bf(float f) {
    unsigned u = __float_as_uint(f);
    u = (u + 0x7fffu + ((u >> 16) & 1u)) >> 16;   // RN-even
    return (unsigned short)u;
}

// Pass A: per-chunk bucket histogram; blkhist[chunk][bucket] (coalesced store)
__global__ void histA_kernel(const int* __restrict__ row, int* __restrict__ blkhist,
                             int NBUK, int E) {
    extern __shared__ int hist[];       // NBUK ints
    for (int i = threadIdx.x; i < NBUK; i += blockDim.x) hist[i] = 0;
    __syncthreads();
    int b = blockIdx.x;
    int s = b * CHUNK, t = min(E, s + CHUNK);
    int nv = (t - s) >> 2;              // int4 groups
    const int4* r4 = (const int4*)(row + s);
    for (int i = threadIdx.x; i < nv; i += blockDim.x) {
        int4 r = r4[i];
        atomicAdd(&hist[r.x >> 7], 1);
        atomicAdd(&hist[r.y >> 7], 1);
        atomicAdd(&hist[r.z >> 7], 1);
        atomicAdd(&hist[r.w >> 7], 1);
    }
    for (int e = s + nv * 4 + threadIdx.x; e < t; e += blockDim.x)
        atomicAdd(&hist[row[e] >> 7], 1);
    __syncthreads();
    int* dst = blkhist + (size_t)b * NBUK;
    for (int k = threadIdx.x; k < NBUK; k += blockDim.x) dst[k] = hist[k];
}

// Pass B: per bucket, exclusive scan over chunks (in place, strided) + total.
// Bucket base in binned[] is b*CAP by construction (no cross-bucket scan).
__global__ void scanB1_kernel(int* __restrict__ blkhist, int* __restrict__ btotal,
                              int NBUK, int NCH) {
    int k = blockIdx.x;
    int lane = threadIdx.x;             // blockDim.x == 64
    int carry = 0;
    for (int base = 0; base < NCH; base += 64) {
        int i = base + lane;
        int v = (i < NCH) ? blkhist[(size_t)i * NBUK + k] : 0;
        int incl = v;
        #pragma unroll
        for (int off = 1; off < 64; off <<= 1) {
            int u = __shfl_up(incl, off, 64);
            if (lane >= off) incl += u;
        }
        if (i < NCH) blkhist[(size_t)i * NBUK + k] = carry + incl - v;
        carry += __shfl(incl, 63, 64);
    }
    if (lane == 0) btotal[k] = carry;
}

// Pass C: scatter edges to fixed-CAP bucket regions, packed (row&127)<<25 | col.
// Guarded against (statistically unreachable) bucket overflow: drop, stay in-bounds.
__global__ void scatC_kernel(const int* __restrict__ row, const int* __restrict__ col,
                             const int* __restrict__ blkhist,
                             unsigned* __restrict__ binned, int NBUK, int E) {
    extern __shared__ int cur[];        // NBUK ints
    int b = blockIdx.x;
    const int* boff = blkhist + (size_t)b * NBUK;
    for (int k = threadIdx.x; k < NBUK; k += blockDim.x)
        cur[k] = k * CAP + boff[k];     // coalesced
    __syncthreads();
    int s = b * CHUNK, t = min(E, s + CHUNK);
    int nv = (t - s) >> 2;
    const int4* r4 = (const int4*)(row + s);
    const int4* c4 = (const int4*)(col + s);
    for (int i = threadIdx.x; i < nv; i += blockDim.x) {
        int4 r = r4[i];
        int4 c = c4[i];
        unsigned k0 = (unsigned)r.x >> 7;
        int p0 = atomicAdd(&cur[k0], 1);
        if (p0 < (int)((k0 + 1) * CAP))
            binned[p0] = ((unsigned)(r.x & (RB - 1)) << RSH) | (unsigned)c.x;
        unsigned k1 = (unsigned)r.y >> 7;
        int p1 = atomicAdd(&cur[k1], 1);
        if (p1 < (int)((k1 + 1) * CAP))
            binned[p1] = ((unsigned)(r.y & (RB - 1)) << RSH) | (unsigned)c.y;
        unsigned k2 = (unsigned)r.z >> 7;
        int p2 = atomicAdd(&cur[k2], 1);
        if (p2 < (int)((k2 + 1) * CAP))
            binned[p2] = ((unsigned)(r.z & (RB - 1)) << RSH) | (unsigned)c.z;
        unsigned k3 = (unsigned)r.w >> 7;
        int p3 = atomicAdd(&cur[k3], 1);
        if (p3 < (int)((k3 + 1) * CAP))
            binned[p3] = ((unsigned)(r.w & (RB - 1)) << RSH) | (unsigned)c.w;
    }
    for (int e = s + nv * 4 + threadIdx.x; e < t; e += blockDim.x) {
        int r = row[e], c = col[e];
        unsigned k0 = (unsigned)r >> 7;
        int pos = atomicAdd(&cur[k0], 1);
        if (pos < (int)((k0 + 1) * CAP))
            binned[pos] = ((unsigned)(r & (RB - 1)) << RSH) | (unsigned)c;
    }
}

// Fused degdis + transform. One block (512 thr) per bucket b == 128-node tile b.
// Phase 1 (all 512): LDS row-hist of binned bucket -> lrp_g, dis (global + LDS).
// Phase 2: stage x,W -> bf16 LDS; all 8 waves MFMA 16 rows each; fused dis scale.
__global__ __launch_bounds__(512)
void distrans_kernel(const int* __restrict__ btotal, const unsigned* __restrict__ binned,
                     const float* __restrict__ x, const float* __restrict__ W,
                     float* __restrict__ dis, int* __restrict__ lrp_g,
                     unsigned short* __restrict__ zp16, int N) {
    __shared__ int hist[RB];
    __shared__ float disS[RB];
    __shared__ unsigned short Xb[RB * 64];   // 16 KB, row stride 64 (K padded)
    __shared__ unsigned short Wb[48 * 64];   // 6 KB, [out][in] = B[k][n] source
    const int b = blockIdx.x;
    const int tid = threadIdx.x;
    const int nb0 = b * RB;
    const int s = b * CAP;
    const int t = s + min(btotal[b], CAP);

    if (tid < RB) hist[tid] = 0;
    __syncthreads();
    for (int e = s + tid; e < t; e += 512)
        atomicAdd(&hist[binned[e] >> RSH], 1);

    // stage x -> Xb (bf16), 1536 float4s (independent of hist; overlaps atomics)
    const float4* x4 = (const float4*)x;
    for (int i = tid; i < RB * 12; i += 512) {
        int r = i / 12, c = i % 12;
        int n = nb0 + r;
        float4 v = (n < N) ? x4[(size_t)n * 12 + c] : make_float4(0.f, 0.f, 0.f, 0.f);
        unsigned short* d = &Xb[r * 64 + c * 4];
        d[0] = f2bf(v.x); d[1] = f2bf(v.y); d[2] = f2bf(v.z); d[3] = f2bf(v.w);
    }
    // zero Xb K-pad (cols 48..63): rows*8 uints
    for (int i = tid; i < RB * 8; i += 512)
        ((unsigned*)Xb)[(i >> 3) * 32 + 24 + (i & 7)] = 0u;
    // stage W -> Wb (bf16), 576 float4s
    const float4* W4 = (const float4*)W;
    for (int i = tid; i < 576; i += 512) {
        int r = i / 12, c = i % 12;
        float4 v = W4[r * 12 + c];
        unsigned short* d = &Wb[r * 64 + c * 4];
        d[0] = f2bf(v.x); d[1] = f2bf(v.y); d[2] = f2bf(v.z); d[3] = f2bf(v.w);
    }
    for (int i = tid; i < 48 * 8; i += 512)
        ((unsigned*)Wb)[(i >> 3) * 32 + 24 + (i & 7)] = 0u;
    __syncthreads();

    // row scan (128 entries, one wave, two 64-passes with carry) -> lrp_g, dis
    if (tid < 64) {
        int* lp = lrp_g + (size_t)b * (RB + 1);
        int carry = 0;
        for (int base = 0; base < RB; base += 64) {
            int i = base + tid;
            int v = hist[i];
            int incl = v;
            #pragma unroll
            for (int off = 1; off < 64; off <<= 1) {
                int u = __shfl_up(incl, off, 64);
                if (tid >= off) incl += u;
            }
            lp[i] = carry + incl - v;
            float dv = (v > 0) ? rsqrtf((float)v) : 0.0f;
            disS[i] = dv;
            int n = nb0 + i;
            if (n < N) dis[n] = dv;
            carry += __shfl(incl, 63, 64);
        }
        if (tid == 0) lp[RB] = carry;
    }
    __syncthreads();

    // all 8 waves: wave wv handles rows [wv*16, wv*16+16)
    const int wv = tid >> 6, lane = tid & 63;
    const int quad = lane >> 4, l16 = lane & 15;
    const int mrow = wv * 16 + l16;

    frag_ab A0 = *(const frag_ab*)&Xb[mrow * 64 + quad * 8];
    frag_ab A1 = *(const frag_ab*)&Xb[mrow * 64 + 32 + quad * 8];
    f32x4 acc[3];
#pragma unroll
    for (int tt = 0; tt < 3; tt++) {
        frag_ab B0 = *(const frag_ab*)&Wb[(tt * 16 + l16) * 64 + quad * 8];
        frag_ab B1 = *(const frag_ab*)&Wb[(tt * 16 + l16) * 64 + 32 + quad * 8];
        f32x4 z = {0.f, 0.f, 0.f, 0.f};
        z = __builtin_amdgcn_mfma_f32_16x16x32_bf16(A0, B0, z, 0, 0, 0);
        z = __builtin_amdgcn_mfma_f32_16x16x32_bf16(A1, B1, z, 0, 0, 0);
        acc[tt] = z;
    }
    // D mapping: col = lane&15 (feature within tile), row = quad*4 + r (node)
#pragma unroll
    for (int r = 0; r < 4; r++) {
        int lrow = wv * 16 + quad * 4 + r;
        int n = nb0 + lrow;
        if (n < N) {
            float dn = disS[lrow];
            unsigned short* zr = zp16 + (size_t)n * (2 * ZLD);
#pragma unroll
            for (int tt = 0; tt < 3; tt++)
                zr[tt * 16 + l16] = f2bf(dn * acc[tt][r]);
            zr[48 + l16] = 0;            // feature pad -> full-line writes
        }
    }
}

// One block (512 thr) per bucket: LDS counting sort by row (cols pre-multiplied x32),
// full-lane unroll-4 gather with fused dis*acc+bias+ReLU epilogue.
__global__ __launch_bounds__(512, 8)
void aggregate_kernel(const int* __restrict__ btotal, const unsigned* __restrict__ binned,
                      const int* __restrict__ lrp_g,
                      const unsigned* __restrict__ zp, const float* __restrict__ dis,
                      const float* __restrict__ bias, float* __restrict__ out, int N) {
    __shared__ int scol[SCOL_CAP];       // 16 KB
    __shared__ int lrp[RB + 1];
    __shared__ int cur[RB];
    const int b = blockIdx.x;
    const int s = b * CAP;
    const int cnt = btotal[b];
    const int t = s + min(cnt, CAP);
    const int tid = threadIdx.x;
    if (tid < RB + 1) {
        int v = lrp_g[(size_t)b * (RB + 1) + tid];
        lrp[tid] = v;
        if (tid < RB) cur[tid] = v;
    }
    __syncthreads();
    const bool sorted = (cnt <= SCOL_CAP);
    if (sorted) {
        for (int e = s + tid; e < t; e += 512) {
            unsigned rc = binned[e];
            int pos = atomicAdd(&cur[rc >> RSH], 1);
            scol[pos] = (int)((rc & CMASK) << 5);   // pre-mult x32 (ZLD)
        }
    }
    __syncthreads();

    const int lane = tid & 63;
    const int wave = tid >> 6;           // 0..7
    const int h = lane >> 5;             // half-wave: edge parity
    const int j = lane & 31;             // feature-pair index (24..31 = pad lanes)
    const bool act = (j < NPAIR);
    const int ja = act ? j : 0;          // inactive lanes alias lane-0's word
    float bb0 = 0.0f, bb1 = 0.0f;
    if (act) { bb0 = bias[2 * j]; bb1 = bias[2 * j + 1]; }
    const int rbase = b * RB;
    for (int ri = wave; ri < RB; ri += 8) {
        int r = rbase + ri;
        if (r >= N) break;
        float a0 = 0.0f, a1 = 0.0f;
        if (sorted) {
            int ks = lrp[ri], ke = lrp[ri + 1];
            int k = ks + h;
            for (; k + 6 < ke; k += 8) {     // unroll 4: edges k,k+2,k+4,k+6 of parity
                int c0 = scol[k];
                int c1 = scol[k + 2];
                int c2 = scol[k + 4];
                int c3 = scol[k + 6];
                unsigned u0 = zp[(size_t)c0 + ja];   // aligned 1-line rows
                unsigned u1 = zp[(size_t)c1 + ja];
                unsigned u2 = zp[(size_t)c2 + ja];
                unsigned u3 = zp[(size_t)c3 + ja];
                a0 += (__uint_as_float(u0 << 16) + __uint_as_float(u1 << 16)) +
                      (__uint_as_float(u2 << 16) + __uint_as_float(u3 << 16));
                a1 += (__uint_as_float(u0 & 0xffff0000u) + __uint_as_float(u1 & 0xffff0000u)) +
                      (__uint_as_float(u2 & 0xffff0000u) + __uint_as_float(u3 & 0xffff0000u));
            }
            for (; k < ke; k += 2) {
                int c0 = scol[k];
                unsigned u0 = zp[(size_t)c0 + ja];
                a0 += __uint_as_float(u0 << 16);
                a1 += __uint_as_float(u0 & 0xffff0000u);
            }
        } else {                         // overflow fallback (statistically unreachable)
            for (int e = s; e < t; e++) {
                unsigned rc = binned[e];
                if ((int)(rc >> RSH) == ri && h == 0 && act) {
                    unsigned u0 = zp[((size_t)(rc & CMASK) << 5) + ja];
                    a0 += __uint_as_float(u0 << 16);
                    a1 += __uint_as_float(u0 & 0xffff0000u);
                }
            }
        }
        a0 += __shfl_xor(a0, 32, 64);    // combine edge parities
        a1 += __shfl_xor(a1, 32, 64);
        if (h == 0 && act) {
            float dr = dis[r];
            float v0 = dr * a0 + bb0;
            float v1 = dr * a1 + bb1;
            float2 o;
            o.x = v0 > 0.0f ? v0 : 0.0f;
            o.y = v1 > 0.0f ? v1 : 0.0f;
            *(float2*)(out + (size_t)r * NF + 2 * j) = o;
        }
    }
}

extern "C" void kernel_launch(void* const* d_in, const int* in_sizes, int n_in,
                              void* d_out, int out_size, void* d_ws, size_t ws_size,
                              hipStream_t stream) {
    const float* x    = (const float*)d_in[0];
    const int*   ei   = (const int*)d_in[1];
    const float* W    = (const float*)d_in[2];
    const float* bias = (const float*)d_in[3];
    float* out = (float*)d_out;

    const int N = in_sizes[0] / NF;
    const int E = in_sizes[1] / 2;
    const int* row = ei;                      // edge_index[0]
    const int* col = ei + E;                  // edge_index[1]
    const int NBUK = (N + RB - 1) / RB;       // 782
    const int NCH  = (E + CHUNK - 1) / CHUNK; // 98

    // workspace layout
    char* ws = (char*)d_ws;
    unsigned* zp      = (unsigned*)ws;       ws += (size_t)N * ZLD * 4;          // 12.8 MB
    unsigned* binned  = (unsigned*)ws;       ws += (size_t)NBUK * CAP * 4;       // 12.8 MB
    float*    dis     = (float*)ws;          ws += (size_t)N * 4;
    int*      blkhist = (int*)ws;            ws += (size_t)NCH * NBUK * 4;       // 306 KB
    int*      btotal  = (int*)ws;            ws += (size_t)NBUK * 4;
    int*      lrp_g   = (int*)ws;            ws += (size_t)NBUK * (RB + 1) * 4;  // 403 KB

    histA_kernel<<<NCH, 512, NBUK * 4, stream>>>(row, blkhist, NBUK, E);
    scanB1_kernel<<<NBUK, 64, 0, stream>>>(blkhist, btotal, NBUK, NCH);
    scatC_kernel<<<NCH, 512, NBUK * 4, stream>>>(row, col, blkhist, binned, NBUK, E);
    distrans_kernel<<<NBUK, 512, 0, stream>>>(btotal, binned, x, W, dis, lrp_g,
                                              (unsigned short*)zp, N);
    aggregate_kernel<<<NBUK, 512, 0, stream>>>(btotal, binned, lrp_g, zp, dis, bias, out, N);
}